// Round 3
// baseline (1069.857 us; speedup 1.0000x reference)
//
#include <hip/hip_runtime.h>
#include <stdint.h>
#include <math.h>

// ---------------------------------------------------------------------------
// HippocampalFastWeight on MI355X (gfx950)
// B=8, T=2048, D=512, N=2048, K_CA3=64
// Round 3: global_load_lds (width 16) staging in all GEMMs (m93->m97 ladder);
// Hebbian shift moved out of the GEMM into an explicit STs materialization
// (transpose kernel writes both ST and t+1-shifted STs, zero row at t=T).
// Region plan per batch (8 MiB each): R1 h->W, R2 S->g, R3 ST->succ, R4 STs.
// ---------------------------------------------------------------------------

typedef __attribute__((ext_vector_type(8))) short bf16x8;
typedef __attribute__((ext_vector_type(8))) unsigned short u16x8;
typedef __attribute__((ext_vector_type(4))) float f32x4;

#define GLD_LDS16(gp, lp)                                     \
  __builtin_amdgcn_global_load_lds(                           \
      (const __attribute__((address_space(1))) void*)(gp),    \
      (__attribute__((address_space(3))) void*)(lp), 16, 0, 0)

__device__ __forceinline__ uint16_t f2bf(float f) {
  uint32_t u = __float_as_uint(f);
  uint32_t r = u + 0x7FFFu + ((u >> 16) & 1u);
  return (uint16_t)(r >> 16);
}
__device__ __forceinline__ float bf2f(unsigned u) {
  return __uint_as_float(u << 16);
}

// ------------------------------- cast --------------------------------------
__global__ __launch_bounds__(256) void cast_f32_bf16_k(
    const float* __restrict__ s, uint16_t* __restrict__ d, long long n) {
  long long i = (long long)blockIdx.x * 256 + threadIdx.x;
  long long stride = (long long)gridDim.x * 256;
  for (; i < n; i += stride) d[i] = f2bf(s[i]);
}

// --------------------- transpose up_W (D x N -> N x D) ---------------------
__global__ __launch_bounds__(256) void transpose_upw_k(
    const float* __restrict__ src, float* __restrict__ dst, int D, int N) {
  __shared__ float t[32][33];
  int n0 = blockIdx.x * 32, d0 = blockIdx.y * 32;
  int lx = threadIdx.x & 31, ly = threadIdx.x >> 5;  // 32 x 8
#pragma unroll
  for (int r = 0; r < 4; ++r) {
    int d = d0 + ly + r * 8;
    t[ly + r * 8][lx] = src[(long long)d * N + n0 + lx];
  }
  __syncthreads();
#pragma unroll
  for (int r = 0; r < 4; ++r) {
    int n = n0 + ly + r * 8;
    dst[(long long)n * D + d0 + lx] = t[lx][ly + r * 8];
  }
}

// ------------------------------- GEMM --------------------------------------
// C[M,N] = A[M,K] * B[N,K]^T (bf16 in, fp32 accum). 128x128 tile, BK=32,
// 256 threads = 4 waves (2x2), wave does 64x64 via 4x4 of 16x16x32 MFMA.
// Staging: global_load_lds width 16 — wave-uniform LDS base + lane*16.
#define EPI_RELU_BF16 0
#define EPI_DIAG0 1
#define EPI_SIG 2

template <int EPI>
__global__ __launch_bounds__(256) void gemm_bt_k(
    const uint16_t* __restrict__ A, const uint16_t* __restrict__ B,
    void* __restrict__ Cv, const float* __restrict__ bias,
    int M, int N, int K, long long sA, long long sB, long long sC) {
  __shared__ __align__(16) uint16_t As[128 * 32];
  __shared__ __align__(16) uint16_t Bs[128 * 32];
  const int b = blockIdx.z;
  const uint16_t* Ab = A + (long long)b * sA;
  const uint16_t* Bb = B + (long long)b * sB;
  const int tid = threadIdx.x;
  const int lane = tid & 63;
  const int wave = tid >> 6;
  const int m0 = blockIdx.x * 128;
  const int n0 = blockIdx.y * 128;
  const int wm = (wave & 1) * 64;
  const int wn = (wave >> 1) * 64;
  const int quad = lane >> 4;
  const int l16 = lane & 15;

  f32x4 acc[4][4];
#pragma unroll
  for (int i = 0; i < 4; ++i)
#pragma unroll
    for (int j = 0; j < 4; ++j) acc[i][j] = (f32x4){0.f, 0.f, 0.f, 0.f};

  // staging geometry: round r in {0,1}; wave covers rows r*64 + wave*16 + lane/4
  // (64B per row of 32 bf16), seg = lane&3 (16B). LDS base is wave-uniform.
  const int srow = wave * 16 + (lane >> 2);  // + r*64
  const int sseg = lane & 3;
  const long long arow0 = (long long)(m0 + srow) * K + sseg * 8;
  const long long brow0 = (long long)(n0 + srow) * K + sseg * 8;

  for (int k0 = 0; k0 < K; k0 += 32) {
#pragma unroll
    for (int r = 0; r < 2; ++r) {
      GLD_LDS16(Ab + arow0 + (long long)r * 64 * K + k0,
                &As[(r * 64 + wave * 16) * 32]);
      GLD_LDS16(Bb + brow0 + (long long)r * 64 * K + k0,
                &Bs[(r * 64 + wave * 16) * 32]);
    }
    __syncthreads();
    bf16x8 af[4], bfr[4];
#pragma unroll
    for (int i = 0; i < 4; ++i)
      af[i] = *(const bf16x8*)(&As[(wm + i * 16 + l16) * 32 + quad * 8]);
#pragma unroll
    for (int j = 0; j < 4; ++j)
      bfr[j] = *(const bf16x8*)(&Bs[(wn + j * 16 + l16) * 32 + quad * 8]);
#pragma unroll
    for (int i = 0; i < 4; ++i)
#pragma unroll
      for (int j = 0; j < 4; ++j)
        acc[i][j] = __builtin_amdgcn_mfma_f32_16x16x32_bf16(af[i], bfr[j], acc[i][j], 0, 0, 0);
    __syncthreads();
  }

  // epilogue: C[m0+wm+i*16+quad*4+r][n0+wn+j*16+l16]
#pragma unroll
  for (int i = 0; i < 4; ++i) {
#pragma unroll
    for (int j = 0; j < 4; ++j) {
#pragma unroll
      for (int r = 0; r < 4; ++r) {
        int row = m0 + wm + i * 16 + quad * 4 + r;
        int col = n0 + wn + j * 16 + l16;
        float v = acc[i][j][r];
        if (EPI == EPI_RELU_BF16) {
          uint16_t* C = (uint16_t*)Cv + (long long)b * sC;
          C[(long long)row * N + col] = f2bf(v > 0.f ? v : 0.f);
        } else if (EPI == EPI_DIAG0) {
          uint16_t* C = (uint16_t*)Cv + (long long)b * sC;
          C[(long long)row * N + col] = (row == col) ? (uint16_t)0 : f2bf(v);
        } else {
          float* C = (float*)Cv + (long long)b * sC;
          float z = v + bias[col];
          C[(long long)row * N + col] = 1.f / (1.f + __expf(-z));
        }
      }
    }
  }
}

// ---------------- transpose + shift: S (TxN) -> ST, STs (NxT) --------------
// ST[n][t] = S[t][n]; STs[n][t] = S[t+1][n], with S[T] == 0.
__global__ __launch_bounds__(256) void transpose_shift_k(
    const uint16_t* __restrict__ S, uint16_t* __restrict__ ST,
    uint16_t* __restrict__ STs, int T, int N) {
  __shared__ uint16_t tile[65][72];  // +8 pad: column reads spread banks
  int t0 = blockIdx.x * 64, n0 = blockIdx.y * 64, b = blockIdx.z;
  const uint16_t* Sb = S + (long long)b * T * N;
  for (int s = threadIdx.x; s < 65 * 8; s += 256) {
    int t = s >> 3, n8 = s & 7;
    u16x8 v = (u16x8){0, 0, 0, 0, 0, 0, 0, 0};
    if (t0 + t < T) v = *(const u16x8*)(Sb + (long long)(t0 + t) * N + n0 + n8 * 8);
    *(u16x8*)(&tile[t][n8 * 8]) = v;
  }
  __syncthreads();
  uint16_t* STb = ST + (long long)b * N * T;
  uint16_t* STsb = STs + (long long)b * N * T;
  for (int s = threadIdx.x; s < 64 * 8; s += 256) {
    int n = s >> 3, t8 = s & 7;
    u16x8 a, c;
#pragma unroll
    for (int j = 0; j < 8; ++j) {
      a[j] = tile[t8 * 8 + j][n];
      c[j] = tile[t8 * 8 + j + 1][n];
    }
    *(u16x8*)(STb + (long long)(n0 + n) * T + t0 + t8 * 8) = a;
    *(u16x8*)(STsb + (long long)(n0 + n) * T + t0 + t8 * 8) = c;
  }
}

// -------------- exact top-64 + L2 normalize, bf16 keys (N=2048) ------------
// 2-pass radix over the 16-bit bf16 pattern (values >= 0 so uint order ==
// float order). Ties filled lowest-index-first (matches lax.top_k).
template <int SPARSE>
__global__ __launch_bounds__(256) void topk_bf16_k(
    const uint16_t* __restrict__ H, uint16_t* __restrict__ Sout,
    int* __restrict__ idxo, float* __restrict__ valo) {
  const long long row = blockIdx.x;
  const uint16_t* h = H + row * 2048;
  const int tid = threadIdx.x;
  u16x8 v = *(const u16x8*)(h + tid * 8);

  __shared__ int hist[256];
  __shared__ int scan[256];
  __shared__ int sel_bin, sel_need;
  __shared__ int cgt_sh;
  __shared__ float ss_sh;
  __shared__ int app_sh;

  hist[tid] = 0;
  if (tid == 0) { cgt_sh = 0; ss_sh = 0.f; app_sh = 0; }
  __syncthreads();
#pragma unroll
  for (int i = 0; i < 8; ++i) atomicAdd(&hist[v[i] >> 8], 1);
  __syncthreads();
  scan[tid] = hist[tid];
  __syncthreads();
  for (int o = 1; o < 256; o <<= 1) {
    int x = scan[tid] + ((tid + o < 256) ? scan[tid + o] : 0);
    __syncthreads();
    scan[tid] = x;
    __syncthreads();
  }
  if (scan[tid] >= 64 && (tid == 255 || scan[tid + 1] < 64)) {
    sel_bin = tid;
    sel_need = 64 - ((tid == 255) ? 0 : scan[tid + 1]);
  }
  __syncthreads();
  const int b1 = sel_bin;
  const int need1 = sel_need;
  __syncthreads();

  hist[tid] = 0;
  __syncthreads();
#pragma unroll
  for (int i = 0; i < 8; ++i)
    if ((int)(v[i] >> 8) == b1) atomicAdd(&hist[v[i] & 255], 1);
  __syncthreads();
  scan[tid] = hist[tid];
  __syncthreads();
  for (int o = 1; o < 256; o <<= 1) {
    int x = scan[tid] + ((tid + o < 256) ? scan[tid + o] : 0);
    __syncthreads();
    scan[tid] = x;
    __syncthreads();
  }
  if (scan[tid] >= need1 && (tid == 255 || scan[tid + 1] < need1)) sel_bin = tid;
  __syncthreads();
  const unsigned thresh = ((unsigned)b1 << 8) | (unsigned)sel_bin;
  const float thf = bf2f(thresh);

  int cgt = 0, ctie = 0;
  float ssq = 0.f;
#pragma unroll
  for (int i = 0; i < 8; ++i) {
    unsigned u = v[i];
    if (u > thresh) { cgt++; float f = bf2f(u); ssq += f * f; }
    else if (u == thresh) ctie++;
  }
  atomicAdd(&cgt_sh, cgt);
  atomicAdd(&ss_sh, ssq);
  __syncthreads();
  scan[tid] = ctie;
  __syncthreads();
  for (int o = 1; o < 256; o <<= 1) {
    int x = scan[tid] + ((tid >= o) ? scan[tid - o] : 0);
    __syncthreads();
    scan[tid] = x;
    __syncthreads();
  }
  const int tie_base = scan[tid] - ctie;
  const int r = 64 - cgt_sh;
  const float sumsq = ss_sh + (float)r * thf * thf;
  const float inv = 1.f / fmaxf(sqrtf(sumsq), 1e-10f);

  if (SPARSE) {
    int tseen = 0;
#pragma unroll
    for (int i = 0; i < 8; ++i) {
      unsigned u = v[i];
      bool sel = (u > thresh);
      if (u == thresh) { sel = (tie_base + tseen) < r; tseen++; }
      if (sel) {
        int p = atomicAdd(&app_sh, 1);
        idxo[row * 64 + p] = tid * 8 + i;
        valo[row * 64 + p] = bf2f(u) * inv;
      }
    }
  } else {
    u16x8 o16;
    int tseen = 0;
#pragma unroll
    for (int i = 0; i < 8; ++i) {
      unsigned u = v[i];
      bool sel = (u > thresh);
      if (u == thresh) { sel = (tie_base + tseen) < r; tseen++; }
      o16[i] = sel ? (unsigned short)f2bf(bf2f(u) * inv) : (unsigned short)0;
    }
    *(u16x8*)(Sout + row * 2048 + tid * 8) = o16;
  }
}

// ------------------------------- final -------------------------------------
__global__ __launch_bounds__(128) void final_k(
    const float* __restrict__ x, const float* __restrict__ g,
    const float* __restrict__ upT, const int* __restrict__ idxo,
    const float* __restrict__ valo, float* __restrict__ out, int D) {
  long long row = blockIdx.x;
  __shared__ int sidx[64];
  __shared__ float sval[64];
  int tid = threadIdx.x;
  if (tid < 64) {
    sidx[tid] = idxo[row * 64 + tid];
    sval[tid] = valo[row * 64 + tid];
  }
  __syncthreads();
  int d = tid * 4;
  float4 a = {0.f, 0.f, 0.f, 0.f};
#pragma unroll 8
  for (int j = 0; j < 64; ++j) {
    float v = sval[j];
    const float4 u = *(const float4*)(upT + (long long)sidx[j] * D + d);
    a.x = fmaf(v, u.x, a.x);
    a.y = fmaf(v, u.y, a.y);
    a.z = fmaf(v, u.z, a.z);
    a.w = fmaf(v, u.w, a.w);
  }
  long long o = row * D + d;
  const float4 xv = *(const float4*)(x + o);
  const float4 gv = *(const float4*)(g + o);
  float4 rr;
  rr.x = xv.x + gv.x * a.x;
  rr.y = xv.y + gv.y * a.y;
  rr.z = xv.z + gv.z * a.z;
  rr.w = xv.w + gv.w * a.w;
  *(float4*)(out + o) = rr;
}

// ---------------------------------------------------------------------------
extern "C" void kernel_launch(void* const* d_in, const int* in_sizes, int n_in,
                              void* d_out, int out_size, void* d_ws, size_t ws_size,
                              hipStream_t stream) {
  const float* x = (const float*)d_in[0];
  const float* downW = (const float*)d_in[1];
  const float* upW = (const float*)d_in[2];
  const float* gateW = (const float*)d_in[3];
  const float* gateB = (const float*)d_in[4];
  float* out = (float*)d_out;

  const int B = 8, T = 2048, D = 512, N = 2048;
  const long long BT = (long long)B * T;
  const long long TN = (long long)T * N;  // 4,194,304
  const long long NN = (long long)N * N;
  const long long TD = (long long)T * D;

  char* base = (char*)d_ws;
  size_t off = 0;
  auto take = [&](size_t bytes) {
    size_t o = off;
    off += (bytes + 255) & ~(size_t)255;
    return o;
  };
  size_t o_xb = take((size_t)BT * D * 2);  // 16 MiB
  size_t o_dwb = take((size_t)N * D * 2);  // 2 MiB
  size_t o_gwb = take((size_t)D * D * 2);  // 0.5 MiB
  size_t o_upT = take((size_t)N * D * 4);  // 4 MiB
  const size_t fixed = off;
  // per batch: R1..R4 (8 MiB each) + idx + val
  const size_t perb = 4 * (size_t)TN * 2 + (size_t)T * 64 * 4 * 2;  // ~33 MiB
  int Bc = 1;
  if (ws_size >= fixed + 8 * perb) Bc = 8;
  else if (ws_size >= fixed + 4 * perb) Bc = 4;
  else if (ws_size >= fixed + 2 * perb) Bc = 2;

  uint16_t* xb = (uint16_t*)(base + o_xb);
  uint16_t* dwb = (uint16_t*)(base + o_dwb);
  uint16_t* gwb = (uint16_t*)(base + o_gwb);
  float* upT = (float*)(base + o_upT);
  char* p = base + fixed;
  uint16_t* R1 = (uint16_t*)p; p += (size_t)TN * 2 * Bc;  // h -> W
  uint16_t* R2 = (uint16_t*)p; p += (size_t)TN * 2 * Bc;  // S -> g (fp32, 4MiB)
  uint16_t* R3 = (uint16_t*)p; p += (size_t)TN * 2 * Bc;  // ST -> succ
  uint16_t* R4 = (uint16_t*)p; p += (size_t)TN * 2 * Bc;  // STs
  int* idx2 = (int*)p; p += (size_t)T * 64 * 4 * Bc;
  float* val2 = (float*)p;

  // prep (once)
  cast_f32_bf16_k<<<2048, 256, 0, stream>>>(x, xb, BT * D);
  cast_f32_bf16_k<<<512, 256, 0, stream>>>(downW, dwb, (long long)N * D);
  cast_f32_bf16_k<<<128, 256, 0, stream>>>(gateW, gwb, (long long)D * D);
  transpose_upw_k<<<dim3(N / 32, D / 32), 256, 0, stream>>>(upW, upT, D, N);

  for (int b0 = 0; b0 < B; b0 += Bc) {
    const uint16_t* xc = xb + (long long)b0 * TD;
    // h = relu(x @ down_W^T) -> R1
    gemm_bt_k<EPI_RELU_BF16><<<dim3(Bc * 16, 16, 1), 256, 0, stream>>>(
        xc, dwb, R1, nullptr, Bc * T, N, D, 0, 0, 0);
    // S = l2norm(kwta(h)) -> R2 (dense bf16)
    topk_bf16_k<0><<<Bc * T, 256, 0, stream>>>(R1, R2, nullptr, nullptr);
    // ST -> R3, STs -> R4
    transpose_shift_k<<<dim3(T / 64, N / 64, Bc), 256, 0, stream>>>(R2, R3, R4, T, N);
    // W[b] = STs @ ST^T, diag 0 -> R1 (h dead)
    gemm_bt_k<EPI_DIAG0><<<dim3(N / 128, N / 128, Bc), 256, 0, stream>>>(
        R4, R3, R1, nullptr, N, N, T, TN, TN, NN);
    // succ[b] = relu(S @ W^T) -> R3 (ST dead)
    gemm_bt_k<EPI_RELU_BF16><<<dim3(T / 128, N / 128, Bc), 256, 0, stream>>>(
        R2, R1, R3, nullptr, T, N, N, TN, NN, TN);
    // sparse l2norm(kwta(succ))
    topk_bf16_k<1><<<Bc * T, 256, 0, stream>>>(R3, nullptr, idx2, val2);
    // g = sigmoid(x @ gate_W^T + b) -> R2 fp32 (S dead)
    gemm_bt_k<EPI_SIG><<<dim3(Bc * 16, D / 128, 1), 256, 0, stream>>>(
        xc, gwb, R2, gateB, Bc * T, D, D, 0, 0, 0);
    // out = x + g * prediction
    final_k<<<Bc * T, 128, 0, stream>>>(x + (long long)b0 * TD, (const float*)R2,
                                        upT, idx2, val2, out + (long long)b0 * TD, D);
  }
}

// Round 4
// 993.975 us; speedup vs baseline: 1.0763x; 1.0763x over previous
//
#include <hip/hip_runtime.h>
#include <stdint.h>
#include <math.h>

// ---------------------------------------------------------------------------
// HippocampalFastWeight on MI355X (gfx950)
// B=8, T=2048, D=512, N=2048, K_CA3=64
// Round 4: Gram reformulation.
//   G = S·S^T (T×T, symmetric -> lower-triangle tiles + mirror store)
//   w_diag[n] = sum_t S[t+1][n]·S[t][n]
//   succ[t][n] = relu( (G · S_shift)[t][n] − S[t][n]·w_diag[n] )
//   where S_shift^T = STs (the only transposed buffer needed).
// Regions per batch (8 MiB): R1 h->G->  , R2 S->succ (in-place), R3 STs->g.
// ---------------------------------------------------------------------------

typedef __attribute__((ext_vector_type(8))) short bf16x8;
typedef __attribute__((ext_vector_type(8))) unsigned short u16x8;
typedef __attribute__((ext_vector_type(4))) float f32x4;

#define GLD_LDS16(gp, lp)                                     \
  __builtin_amdgcn_global_load_lds(                           \
      (const __attribute__((address_space(1))) void*)(gp),    \
      (__attribute__((address_space(3))) void*)(lp), 16, 0, 0)

__device__ __forceinline__ uint16_t f2bf(float f) {
  uint32_t u = __float_as_uint(f);
  uint32_t r = u + 0x7FFFu + ((u >> 16) & 1u);
  return (uint16_t)(r >> 16);
}
__device__ __forceinline__ float bf2f(unsigned u) {
  return __uint_as_float(u << 16);
}

// ------------------------------- cast --------------------------------------
__global__ __launch_bounds__(256) void cast_f32_bf16_k(
    const float* __restrict__ s, uint16_t* __restrict__ d, long long n) {
  long long i = (long long)blockIdx.x * 256 + threadIdx.x;
  long long stride = (long long)gridDim.x * 256;
  for (; i < n; i += stride) d[i] = f2bf(s[i]);
}

__global__ __launch_bounds__(256) void zero_f32_k(float* __restrict__ p, long long n) {
  long long i = (long long)blockIdx.x * 256 + threadIdx.x;
  if (i < n) p[i] = 0.f;
}

// --------------------- transpose up_W (D x N -> N x D) ---------------------
__global__ __launch_bounds__(256) void transpose_upw_k(
    const float* __restrict__ src, float* __restrict__ dst, int D, int N) {
  __shared__ float t[32][33];
  int n0 = blockIdx.x * 32, d0 = blockIdx.y * 32;
  int lx = threadIdx.x & 31, ly = threadIdx.x >> 5;
#pragma unroll
  for (int r = 0; r < 4; ++r) {
    int d = d0 + ly + r * 8;
    t[ly + r * 8][lx] = src[(long long)d * N + n0 + lx];
  }
  __syncthreads();
#pragma unroll
  for (int r = 0; r < 4; ++r) {
    int n = n0 + ly + r * 8;
    dst[(long long)n * D + d0 + lx] = t[lx][ly + r * 8];
  }
}

// ------------------------------- GEMM --------------------------------------
// C[M,N] = A[M,K] * B[N,K]^T (bf16 in, fp32 accum). 128x128 tile, BK=32,
// global_load_lds width-16 staging.
#define EPI_RELU_BF16 0
#define EPI_SIG 2
#define EPI_SUCC 3

template <int EPI>
__global__ __launch_bounds__(256) void gemm_bt_k(
    const uint16_t* __restrict__ A, const uint16_t* __restrict__ B,
    void* __restrict__ Cv, const float* __restrict__ bias,
    const float* __restrict__ wd,
    int M, int N, int K, long long sA, long long sB, long long sC) {
  __shared__ __align__(16) uint16_t As[128 * 32];
  __shared__ __align__(16) uint16_t Bs[128 * 32];
  const int b = blockIdx.z;
  const uint16_t* Ab = A + (long long)b * sA;
  const uint16_t* Bb = B + (long long)b * sB;
  const int tid = threadIdx.x;
  const int lane = tid & 63;
  const int wave = tid >> 6;
  const int m0 = blockIdx.x * 128;
  const int n0 = blockIdx.y * 128;
  const int wm = (wave & 1) * 64;
  const int wn = (wave >> 1) * 64;
  const int quad = lane >> 4;
  const int l16 = lane & 15;

  f32x4 acc[4][4];
#pragma unroll
  for (int i = 0; i < 4; ++i)
#pragma unroll
    for (int j = 0; j < 4; ++j) acc[i][j] = (f32x4){0.f, 0.f, 0.f, 0.f};

  const int srow = wave * 16 + (lane >> 2);
  const int sseg = lane & 3;
  const long long arow0 = (long long)(m0 + srow) * K + sseg * 8;
  const long long brow0 = (long long)(n0 + srow) * K + sseg * 8;

  for (int k0 = 0; k0 < K; k0 += 32) {
#pragma unroll
    for (int r = 0; r < 2; ++r) {
      GLD_LDS16(Ab + arow0 + (long long)r * 64 * K + k0,
                &As[(r * 64 + wave * 16) * 32]);
      GLD_LDS16(Bb + brow0 + (long long)r * 64 * K + k0,
                &Bs[(r * 64 + wave * 16) * 32]);
    }
    __syncthreads();
    bf16x8 af[4], bfr[4];
#pragma unroll
    for (int i = 0; i < 4; ++i)
      af[i] = *(const bf16x8*)(&As[(wm + i * 16 + l16) * 32 + quad * 8]);
#pragma unroll
    for (int j = 0; j < 4; ++j)
      bfr[j] = *(const bf16x8*)(&Bs[(wn + j * 16 + l16) * 32 + quad * 8]);
#pragma unroll
    for (int i = 0; i < 4; ++i)
#pragma unroll
      for (int j = 0; j < 4; ++j)
        acc[i][j] = __builtin_amdgcn_mfma_f32_16x16x32_bf16(af[i], bfr[j], acc[i][j], 0, 0, 0);
    __syncthreads();
  }

#pragma unroll
  for (int i = 0; i < 4; ++i) {
#pragma unroll
    for (int j = 0; j < 4; ++j) {
#pragma unroll
      for (int r = 0; r < 4; ++r) {
        int row = m0 + wm + i * 16 + quad * 4 + r;
        int col = n0 + wn + j * 16 + l16;
        float v = acc[i][j][r];
        if (EPI == EPI_RELU_BF16) {
          uint16_t* C = (uint16_t*)Cv + (long long)b * sC;
          C[(long long)row * N + col] = f2bf(v > 0.f ? v : 0.f);
        } else if (EPI == EPI_SUCC) {
          // C aliases S (bf16): succ = relu(v - S[row][col]*wd[col]), in-place
          uint16_t* C = (uint16_t*)Cv + (long long)b * sC;
          long long o = (long long)row * N + col;
          float sv = bf2f(C[o]);
          float v2 = v - sv * wd[(long long)b * N + col];
          C[o] = f2bf(v2 > 0.f ? v2 : 0.f);
        } else {
          float* C = (float*)Cv + (long long)b * sC;
          float z = v + bias[col];
          C[(long long)row * N + col] = 1.f / (1.f + __expf(-z));
        }
      }
    }
  }
}

// --------------------- Gram GEMM: G = S·S^T, symmetric ---------------------
// Lower-triangle tile grid (136 tiles for 16x16), mirror store for ti!=tj.
__global__ __launch_bounds__(256) void gram_k(
    const uint16_t* __restrict__ S, uint16_t* __restrict__ G,
    int T, int N, long long sS, long long sG) {
  __shared__ __align__(16) uint16_t As[128 * 32];
  __shared__ __align__(16) uint16_t Bs[128 * 32];
  const int b = blockIdx.z;
  const uint16_t* Sb = S + (long long)b * sS;
  uint16_t* Gb = G + (long long)b * sG;
  // linear lower-triangle index -> (ti, tj), ti >= tj
  int idx = blockIdx.x;
  int ti = 0;
  while ((ti + 1) * (ti + 2) / 2 <= idx) ti++;
  int tj = idx - ti * (ti + 1) / 2;
  const int m0 = ti * 128;
  const int n0 = tj * 128;
  const int tid = threadIdx.x;
  const int lane = tid & 63;
  const int wave = tid >> 6;
  const int wm = (wave & 1) * 64;
  const int wn = (wave >> 1) * 64;
  const int quad = lane >> 4;
  const int l16 = lane & 15;
  const int K = N;

  f32x4 acc[4][4];
#pragma unroll
  for (int i = 0; i < 4; ++i)
#pragma unroll
    for (int j = 0; j < 4; ++j) acc[i][j] = (f32x4){0.f, 0.f, 0.f, 0.f};

  const int srow = wave * 16 + (lane >> 2);
  const int sseg = lane & 3;
  const long long arow0 = (long long)(m0 + srow) * K + sseg * 8;
  const long long brow0 = (long long)(n0 + srow) * K + sseg * 8;

  for (int k0 = 0; k0 < K; k0 += 32) {
#pragma unroll
    for (int r = 0; r < 2; ++r) {
      GLD_LDS16(Sb + arow0 + (long long)r * 64 * K + k0,
                &As[(r * 64 + wave * 16) * 32]);
      GLD_LDS16(Sb + brow0 + (long long)r * 64 * K + k0,
                &Bs[(r * 64 + wave * 16) * 32]);
    }
    __syncthreads();
    bf16x8 af[4], bfr[4];
#pragma unroll
    for (int i = 0; i < 4; ++i)
      af[i] = *(const bf16x8*)(&As[(wm + i * 16 + l16) * 32 + quad * 8]);
#pragma unroll
    for (int j = 0; j < 4; ++j)
      bfr[j] = *(const bf16x8*)(&Bs[(wn + j * 16 + l16) * 32 + quad * 8]);
#pragma unroll
    for (int i = 0; i < 4; ++i)
#pragma unroll
      for (int j = 0; j < 4; ++j)
        acc[i][j] = __builtin_amdgcn_mfma_f32_16x16x32_bf16(af[i], bfr[j], acc[i][j], 0, 0, 0);
    __syncthreads();
  }

#pragma unroll
  for (int i = 0; i < 4; ++i) {
#pragma unroll
    for (int j = 0; j < 4; ++j) {
      uint16_t bv[4];
#pragma unroll
      for (int r = 0; r < 4; ++r) {
        int row = m0 + wm + i * 16 + quad * 4 + r;
        int col = n0 + wn + j * 16 + l16;
        uint16_t h = f2bf(acc[i][j][r]);
        bv[r] = h;
        Gb[(long long)row * T + col] = h;
      }
      if (ti != tj) {
        // mirror: G[col][rowbase..rowbase+3], 8B packed store (4-elem aligned)
        int mrow = n0 + wn + j * 16 + l16;
        int mcol = m0 + wm + i * 16 + quad * 4;
        ushort4 pk = {bv[0], bv[1], bv[2], bv[3]};
        *(ushort4*)(&Gb[(long long)mrow * T + mcol]) = pk;
      }
    }
  }
}

// ---------------- transpose + shift: S (TxN) -> STs (NxT) ------------------
// STs[n][t] = S[t+1][n], zero at t = T-1.
__global__ __launch_bounds__(256) void transpose_shift_k(
    const uint16_t* __restrict__ S, uint16_t* __restrict__ STs, int T, int N) {
  __shared__ uint16_t tile[65][72];
  int t0 = blockIdx.x * 64, n0 = blockIdx.y * 64, b = blockIdx.z;
  const uint16_t* Sb = S + (long long)b * T * N;
  for (int s = threadIdx.x; s < 65 * 8; s += 256) {
    int t = s >> 3, n8 = s & 7;
    u16x8 v = (u16x8){0, 0, 0, 0, 0, 0, 0, 0};
    if (t0 + t + 1 <= T - 1 || (t0 + t + 1 <= T && t > 0) ) {}
    // load rows t0+1 .. t0+64 (shifted window), zero past T-1
    if (t0 + t + 1 < T || (t0 + t + 1 == T)) {
      if (t0 + t + 1 < T)
        v = *(const u16x8*)(Sb + (long long)(t0 + t + 1) * N + n0 + n8 * 8);
      else if (t0 + t + 1 == T - 0 && false) {}
    }
    if (t0 + t + 1 >= T) v = (u16x8){0, 0, 0, 0, 0, 0, 0, 0};
    tile[t][n8 * 8] = v[0];
    *(u16x8*)(&tile[t][n8 * 8]) = v;
  }
  __syncthreads();
  uint16_t* STsb = STs + (long long)b * N * T;
  for (int s = threadIdx.x; s < 64 * 8; s += 256) {
    int n = s >> 3, t8 = s & 7;
    u16x8 c;
#pragma unroll
    for (int j = 0; j < 8; ++j) c[j] = tile[t8 * 8 + j][n];
    *(u16x8*)(STsb + (long long)(n0 + n) * T + t0 + t8 * 8) = c;
  }
}

// ------------------- w_diag[n] = sum_t S[t][n]*S[t+1][n] -------------------
__global__ __launch_bounds__(256) void wdiag_k(
    const uint16_t* __restrict__ S, float* __restrict__ wd, int T, int N) {
  const int b = blockIdx.z;
  const uint16_t* Sb = S + (long long)b * T * N;
  const int n = blockIdx.x * 256 + threadIdx.x;
  const int t0 = blockIdx.y * 256;
  int t1 = t0 + 256;
  if (t1 > T - 1) t1 = T - 1;
  float acc = 0.f;
  for (int t = t0; t < t1; ++t)
    acc += bf2f(Sb[(long long)t * N + n]) * bf2f(Sb[(long long)(t + 1) * N + n]);
  atomicAdd(&wd[(long long)b * N + n], acc);
}

// -------------- exact top-64 + L2 normalize, bf16 keys (N=2048) ------------
template <int SPARSE>
__global__ __launch_bounds__(256) void topk_bf16_k(
    const uint16_t* __restrict__ H, uint16_t* __restrict__ Sout,
    int* __restrict__ idxo, float* __restrict__ valo) {
  const long long row = blockIdx.x;
  const uint16_t* h = H + row * 2048;
  const int tid = threadIdx.x;
  u16x8 v = *(const u16x8*)(h + tid * 8);

  __shared__ int hist[256];
  __shared__ int scan[256];
  __shared__ int sel_bin, sel_need;
  __shared__ int cgt_sh;
  __shared__ float ss_sh;
  __shared__ int app_sh;

  hist[tid] = 0;
  if (tid == 0) { cgt_sh = 0; ss_sh = 0.f; app_sh = 0; }
  __syncthreads();
#pragma unroll
  for (int i = 0; i < 8; ++i) atomicAdd(&hist[v[i] >> 8], 1);
  __syncthreads();
  scan[tid] = hist[tid];
  __syncthreads();
  for (int o = 1; o < 256; o <<= 1) {
    int x = scan[tid] + ((tid + o < 256) ? scan[tid + o] : 0);
    __syncthreads();
    scan[tid] = x;
    __syncthreads();
  }
  if (scan[tid] >= 64 && (tid == 255 || scan[tid + 1] < 64)) {
    sel_bin = tid;
    sel_need = 64 - ((tid == 255) ? 0 : scan[tid + 1]);
  }
  __syncthreads();
  const int b1 = sel_bin;
  const int need1 = sel_need;
  __syncthreads();

  hist[tid] = 0;
  __syncthreads();
#pragma unroll
  for (int i = 0; i < 8; ++i)
    if ((int)(v[i] >> 8) == b1) atomicAdd(&hist[v[i] & 255], 1);
  __syncthreads();
  scan[tid] = hist[tid];
  __syncthreads();
  for (int o = 1; o < 256; o <<= 1) {
    int x = scan[tid] + ((tid + o < 256) ? scan[tid + o] : 0);
    __syncthreads();
    scan[tid] = x;
    __syncthreads();
  }
  if (scan[tid] >= need1 && (tid == 255 || scan[tid + 1] < need1)) sel_bin = tid;
  __syncthreads();
  const unsigned thresh = ((unsigned)b1 << 8) | (unsigned)sel_bin;
  const float thf = bf2f(thresh);

  int cgt = 0, ctie = 0;
  float ssq = 0.f;
#pragma unroll
  for (int i = 0; i < 8; ++i) {
    unsigned u = v[i];
    if (u > thresh) { cgt++; float f = bf2f(u); ssq += f * f; }
    else if (u == thresh) ctie++;
  }
  atomicAdd(&cgt_sh, cgt);
  atomicAdd(&ss_sh, ssq);
  __syncthreads();
  scan[tid] = ctie;
  __syncthreads();
  for (int o = 1; o < 256; o <<= 1) {
    int x = scan[tid] + ((tid >= o) ? scan[tid - o] : 0);
    __syncthreads();
    scan[tid] = x;
    __syncthreads();
  }
  const int tie_base = scan[tid] - ctie;
  const int r = 64 - cgt_sh;
  const float sumsq = ss_sh + (float)r * thf * thf;
  const float inv = 1.f / fmaxf(sqrtf(sumsq), 1e-10f);

  if (SPARSE) {
    int tseen = 0;
#pragma unroll
    for (int i = 0; i < 8; ++i) {
      unsigned u = v[i];
      bool sel = (u > thresh);
      if (u == thresh) { sel = (tie_base + tseen) < r; tseen++; }
      if (sel) {
        int p = atomicAdd(&app_sh, 1);
        idxo[row * 64 + p] = tid * 8 + i;
        valo[row * 64 + p] = bf2f(u) * inv;
      }
    }
  } else {
    u16x8 o16;
    int tseen = 0;
#pragma unroll
    for (int i = 0; i < 8; ++i) {
      unsigned u = v[i];
      bool sel = (u > thresh);
      if (u == thresh) { sel = (tie_base + tseen) < r; tseen++; }
      o16[i] = sel ? (unsigned short)f2bf(bf2f(u) * inv) : (unsigned short)0;
    }
    *(u16x8*)(Sout + row * 2048 + tid * 8) = o16;
  }
}

// ------------------------------- final -------------------------------------
__global__ __launch_bounds__(128) void final_k(
    const float* __restrict__ x, const float* __restrict__ g,
    const float* __restrict__ upT, const int* __restrict__ idxo,
    const float* __restrict__ valo, float* __restrict__ out, int D) {
  long long row = blockIdx.x;
  __shared__ int sidx[64];
  __shared__ float sval[64];
  int tid = threadIdx.x;
  if (tid < 64) {
    sidx[tid] = idxo[row * 64 + tid];
    sval[tid] = valo[row * 64 + tid];
  }
  __syncthreads();
  int d = tid * 4;
  float4 a = {0.f, 0.f, 0.f, 0.f};
#pragma unroll 8
  for (int j = 0; j < 64; ++j) {
    float v = sval[j];
    const float4 u = *(const float4*)(upT + (long long)sidx[j] * D + d);
    a.x = fmaf(v, u.x, a.x);
    a.y = fmaf(v, u.y, a.y);
    a.z = fmaf(v, u.z, a.z);
    a.w = fmaf(v, u.w, a.w);
  }
  long long o = row * D + d;
  const float4 xv = *(const float4*)(x + o);
  const float4 gv = *(const float4*)(g + o);
  float4 rr;
  rr.x = xv.x + gv.x * a.x;
  rr.y = xv.y + gv.y * a.y;
  rr.z = xv.z + gv.z * a.z;
  rr.w = xv.w + gv.w * a.w;
  *(float4*)(out + o) = rr;
}

// ---------------------------------------------------------------------------
extern "C" void kernel_launch(void* const* d_in, const int* in_sizes, int n_in,
                              void* d_out, int out_size, void* d_ws, size_t ws_size,
                              hipStream_t stream) {
  const float* x = (const float*)d_in[0];
  const float* downW = (const float*)d_in[1];
  const float* upW = (const float*)d_in[2];
  const float* gateW = (const float*)d_in[3];
  const float* gateB = (const float*)d_in[4];
  float* out = (float*)d_out;

  const int B = 8, T = 2048, D = 512, N = 2048;
  const long long BT = (long long)B * T;
  const long long TN = (long long)T * N;  // == T*T == N*N
  const long long TD = (long long)T * D;

  char* base = (char*)d_ws;
  size_t off = 0;
  auto take = [&](size_t bytes) {
    size_t o = off;
    off += (bytes + 255) & ~(size_t)255;
    return o;
  };
  size_t o_xb = take((size_t)BT * D * 2);
  size_t o_dwb = take((size_t)N * D * 2);
  size_t o_gwb = take((size_t)D * D * 2);
  size_t o_upT = take((size_t)N * D * 4);
  const size_t fixed = off;
  // per batch: R1 (h->G), R2 (S->succ), R3 (STs->g), wdiag, idx, val
  const size_t perb = 3 * (size_t)TN * 2 + (size_t)N * 4 +
                      (size_t)T * 64 * 4 * 2;
  int Bc = 1;
  if (ws_size >= fixed + 8 * perb) Bc = 8;
  else if (ws_size >= fixed + 4 * perb) Bc = 4;
  else if (ws_size >= fixed + 2 * perb) Bc = 2;

  uint16_t* xb = (uint16_t*)(base + o_xb);
  uint16_t* dwb = (uint16_t*)(base + o_dwb);
  uint16_t* gwb = (uint16_t*)(base + o_gwb);
  float* upT = (float*)(base + o_upT);
  char* p = base + fixed;
  uint16_t* R1 = (uint16_t*)p; p += (size_t)TN * 2 * Bc;  // h -> G
  uint16_t* R2 = (uint16_t*)p; p += (size_t)TN * 2 * Bc;  // S -> succ (in-place)
  uint16_t* R3 = (uint16_t*)p; p += (size_t)TN * 2 * Bc;  // STs -> g (fp32)
  float* wdiag = (float*)p; p += (size_t)N * 4 * Bc;
  int* idx2 = (int*)p; p += (size_t)T * 64 * 4 * Bc;
  float* val2 = (float*)p;

  // prep (once)
  cast_f32_bf16_k<<<2048, 256, 0, stream>>>(x, xb, BT * D);
  cast_f32_bf16_k<<<512, 256, 0, stream>>>(downW, dwb, (long long)N * D);
  cast_f32_bf16_k<<<128, 256, 0, stream>>>(gateW, gwb, (long long)D * D);
  transpose_upw_k<<<dim3(N / 32, D / 32), 256, 0, stream>>>(upW, upT, D, N);

  const int ntile = 16;                       // T/128
  const int ltri = ntile * (ntile + 1) / 2;   // 136

  for (int b0 = 0; b0 < B; b0 += Bc) {
    const uint16_t* xc = xb + (long long)b0 * TD;
    // h = relu(x @ down_W^T) -> R1
    gemm_bt_k<EPI_RELU_BF16><<<dim3(Bc * 16, 16, 1), 256, 0, stream>>>(
        xc, dwb, R1, nullptr, nullptr, Bc * T, N, D, 0, 0, 0);
    // S = l2norm(kwta(h)) -> R2 (dense bf16)
    topk_bf16_k<0><<<Bc * T, 256, 0, stream>>>(R1, R2, nullptr, nullptr);
    // STs -> R3
    transpose_shift_k<<<dim3(T / 64, N / 64, Bc), 256, 0, stream>>>(R2, R3, T, N);
    // w_diag
    zero_f32_k<<<(Bc * N + 255) / 256, 256, 0, stream>>>(wdiag, (long long)Bc * N);
    wdiag_k<<<dim3(N / 256, 8, Bc), 256, 0, stream>>>(R2, wdiag, T, N);
    // G = S·S^T (symmetric) -> R1 (h dead)
    gram_k<<<dim3(ltri, 1, Bc), 256, 0, stream>>>(R2, R1, T, N, TN, TN);
    // succ = relu(G @ STs^T - S*wd) -> R2 in place
    gemm_bt_k<EPI_SUCC><<<dim3(16, 16, Bc), 256, 0, stream>>>(
        R1, R3, R2, nullptr, wdiag, T, N, T, TN, TN, TN);
    // sparse l2norm(kwta(succ))
    topk_bf16_k<1><<<Bc * T, 256, 0, stream>>>(R2, nullptr, idx2, val2);
    // g = sigmoid(x @ gate_W^T + b) -> R3 fp32 (STs dead)
    gemm_bt_k<EPI_SIG><<<dim3(Bc * 16, D / 128, 1), 256, 0, stream>>>(
        xc, gwb, R3, gateB, nullptr, Bc * T, D, D, 0, 0, 0);
    // out = x + g * prediction
    final_k<<<Bc * T, 128, 0, stream>>>(x + (long long)b0 * TD, (const float*)R3,
                                        upT, idx2, val2, out + (long long)b0 * TD, D);
  }
}

// Round 5
// 888.099 us; speedup vs baseline: 1.2047x; 1.1192x over previous
//
#include <hip/hip_runtime.h>
#include <stdint.h>
#include <math.h>

// ---------------------------------------------------------------------------
// HippocampalFastWeight on MI355X (gfx950)
// B=8, T=2048, D=512, N=2048, K_CA3=64
// Round 5: fp8 e4m3 gram + succ GEMMs (m145 ladder), fused wdiag into
// transpose, fused final into topk2, bf16 upT.
// Pipeline per chunk (Bc batches):
//   gemm1 (bf16): h = relu(x @ down_W^T)        -> R1 (bf16)
//   topk1: S = l2norm(kwta(h,64))               -> R2 (bf16) + R4 (fp8)
//   transpose+wd: STs[n][t]=S[t+1][n] (fp8)     -> R3 ; wd[n]=sum S[t]S[t+1]
//   gram (fp8): G = S·S^T, symmetric lower-tri  -> R1 (fp8, over dead h)
//   succ (fp8): succ = relu(G@STs^T - S*wd)     -> R2 in-place (bf16)
//   gate (bf16): g = sigmoid(x @ gate_W^T + b)  -> R3 fp32 (over dead STs)
//   topk2+final: out = x + g * sum val_j*upT[idx_j]
// ---------------------------------------------------------------------------

typedef __attribute__((ext_vector_type(8))) short bf16x8;
typedef __attribute__((ext_vector_type(8))) unsigned short u16x8;
typedef __attribute__((ext_vector_type(8))) unsigned char u8x8;
typedef __attribute__((ext_vector_type(4))) float f32x4;

#define GLD_LDS16(gp, lp)                                     \
  __builtin_amdgcn_global_load_lds(                           \
      (const __attribute__((address_space(1))) void*)(gp),    \
      (__attribute__((address_space(3))) void*)(lp), 16, 0, 0)

__device__ __forceinline__ uint16_t f2bf(float f) {
  uint32_t u = __float_as_uint(f);
  uint32_t r = u + 0x7FFFu + ((u >> 16) & 1u);
  return (uint16_t)(r >> 16);
}
__device__ __forceinline__ float bf2f(unsigned u) {
  return __uint_as_float(u << 16);
}

// f32 -> fp8 e4m3fn (inputs are non-negative and < 448 in this kernel)
__device__ __forceinline__ uint8_t f2fp8(float f) {
#if __has_builtin(__builtin_amdgcn_cvt_pk_fp8_f32)
  return (uint8_t)(__builtin_amdgcn_cvt_pk_fp8_f32(f, 0.f, 0, false) & 0xFF);
#else
  if (!(f > 0.f)) return 0;
  if (f >= 448.f) return 0x7E;
  uint32_t u = __float_as_uint(f);
  int e = (int)((u >> 23) & 255) - 127;
  uint32_t m = u & 0x7FFFFFu;
  if (e < -6) {  // subnormal: round f * 2^9
    float q = f * 512.f;
    int qi = (int)(q + 0.5f);
    if (qi > 7) return 0x08;
    return (uint8_t)qi;
  }
  uint32_t keep = m >> 20;
  uint32_t rem = m & 0xFFFFFu;
  if (rem > 0x80000u || (rem == 0x80000u && (keep & 1))) keep++;
  uint32_t ee = (uint32_t)(e + 7);
  if (keep == 8) { keep = 0; ee++; }
  if (ee >= 16) return 0x7E;
  return (uint8_t)((ee << 3) | keep);
#endif
}

// ------------------------------- cast --------------------------------------
__global__ __launch_bounds__(256) void cast_f32_bf16_k(
    const float* __restrict__ s, uint16_t* __restrict__ d, long long n) {
  long long i = (long long)blockIdx.x * 256 + threadIdx.x;
  long long stride = (long long)gridDim.x * 256;
  for (; i < n; i += stride) d[i] = f2bf(s[i]);
}

__global__ __launch_bounds__(256) void zero_f32_k(float* __restrict__ p, long long n) {
  long long i = (long long)blockIdx.x * 256 + threadIdx.x;
  if (i < n) p[i] = 0.f;
}

// ------------- transpose up_W (D x N fp32 -> N x D bf16) -------------------
__global__ __launch_bounds__(256) void transpose_upw_k(
    const float* __restrict__ src, uint16_t* __restrict__ dst, int D, int N) {
  __shared__ float t[32][33];
  int n0 = blockIdx.x * 32, d0 = blockIdx.y * 32;
  int lx = threadIdx.x & 31, ly = threadIdx.x >> 5;
#pragma unroll
  for (int r = 0; r < 4; ++r) {
    int d = d0 + ly + r * 8;
    t[ly + r * 8][lx] = src[(long long)d * N + n0 + lx];
  }
  __syncthreads();
#pragma unroll
  for (int r = 0; r < 4; ++r) {
    int n = n0 + ly + r * 8;
    dst[(long long)n * D + d0 + lx] = f2bf(t[lx][ly + r * 8]);
  }
}

// --------------------------- bf16 GEMM -------------------------------------
// C[M,N] = A[M,K]*B[N,K]^T, 128x128 tile, BK=32, global_load_lds staging.
#define EPI_RELU_BF16 0
#define EPI_SIG 2

template <int EPI>
__global__ __launch_bounds__(256) void gemm_bt_k(
    const uint16_t* __restrict__ A, const uint16_t* __restrict__ B,
    void* __restrict__ Cv, const float* __restrict__ bias,
    int M, int N, int K) {
  __shared__ __align__(16) uint16_t As[128 * 32];
  __shared__ __align__(16) uint16_t Bs[128 * 32];
  const int tid = threadIdx.x;
  const int lane = tid & 63;
  const int wave = tid >> 6;
  const int m0 = blockIdx.x * 128;
  const int n0 = blockIdx.y * 128;
  const int wm = (wave & 1) * 64;
  const int wn = (wave >> 1) * 64;
  const int quad = lane >> 4;
  const int l16 = lane & 15;

  f32x4 acc[4][4];
#pragma unroll
  for (int i = 0; i < 4; ++i)
#pragma unroll
    for (int j = 0; j < 4; ++j) acc[i][j] = (f32x4){0.f, 0.f, 0.f, 0.f};

  const int srow = wave * 16 + (lane >> 2);
  const int sseg = lane & 3;
  const long long arow0 = (long long)(m0 + srow) * K + sseg * 8;
  const long long brow0 = (long long)(n0 + srow) * K + sseg * 8;

  for (int k0 = 0; k0 < K; k0 += 32) {
#pragma unroll
    for (int r = 0; r < 2; ++r) {
      GLD_LDS16(A + arow0 + (long long)r * 64 * K + k0,
                &As[(r * 64 + wave * 16) * 32]);
      GLD_LDS16(B + brow0 + (long long)r * 64 * K + k0,
                &Bs[(r * 64 + wave * 16) * 32]);
    }
    __syncthreads();
    bf16x8 af[4], bfr[4];
#pragma unroll
    for (int i = 0; i < 4; ++i)
      af[i] = *(const bf16x8*)(&As[(wm + i * 16 + l16) * 32 + quad * 8]);
#pragma unroll
    for (int j = 0; j < 4; ++j)
      bfr[j] = *(const bf16x8*)(&Bs[(wn + j * 16 + l16) * 32 + quad * 8]);
#pragma unroll
    for (int i = 0; i < 4; ++i)
#pragma unroll
      for (int j = 0; j < 4; ++j)
        acc[i][j] = __builtin_amdgcn_mfma_f32_16x16x32_bf16(af[i], bfr[j], acc[i][j], 0, 0, 0);
    __syncthreads();
  }

#pragma unroll
  for (int i = 0; i < 4; ++i) {
#pragma unroll
    for (int j = 0; j < 4; ++j) {
#pragma unroll
      for (int r = 0; r < 4; ++r) {
        int row = m0 + wm + i * 16 + quad * 4 + r;
        int col = n0 + wn + j * 16 + l16;
        float v = acc[i][j][r];
        if (EPI == EPI_RELU_BF16) {
          uint16_t* C = (uint16_t*)Cv;
          C[(long long)row * N + col] = f2bf(v > 0.f ? v : 0.f);
        } else {
          float* C = (float*)Cv;
          float z = v + bias[col];
          C[(long long)row * N + col] = 1.f / (1.f + __expf(-z));
        }
      }
    }
  }
}

// --------------------- fp8 Gram GEMM: G = S·S^T ----------------------------
// Lower-triangle tile grid (136 tiles), mirror store, fp8 in / fp8 out.
__global__ __launch_bounds__(256) void gram_fp8_k(
    const uint8_t* __restrict__ S, uint8_t* __restrict__ G,
    long long sS, long long sG) {
  __shared__ __align__(16) uint8_t As[128 * 32];
  __shared__ __align__(16) uint8_t Bs[128 * 32];
  const int b = blockIdx.z;
  const uint8_t* Sb = S + (long long)b * sS;
  uint8_t* Gb = G + (long long)b * sG;
  int idx = blockIdx.x;
  int ti = 0;
  while ((ti + 1) * (ti + 2) / 2 <= idx) ti++;
  int tj = idx - ti * (ti + 1) / 2;
  const int m0 = ti * 128;
  const int n0 = tj * 128;
  const int tid = threadIdx.x;
  const int lane = tid & 63;
  const int wave = tid >> 6;
  const int wm = (wave & 1) * 64;
  const int wn = (wave >> 1) * 64;
  const int quad = lane >> 4;
  const int l16 = lane & 15;
  const int K = 2048, T = 2048;

  f32x4 acc[4][4];
#pragma unroll
  for (int i = 0; i < 4; ++i)
#pragma unroll
    for (int j = 0; j < 4; ++j) acc[i][j] = (f32x4){0.f, 0.f, 0.f, 0.f};

  // staging: 128 rows x 32 B per k-tile; wave w stages rows w*32..w*32+31,
  // lane l -> row w*32 + (l>>1), half (l&1)*16. One GLD per matrix per iter.
  const int srow = wave * 32 + (lane >> 1);
  const int shalf = lane & 1;
  const long long arow0 = (long long)(m0 + srow) * K + shalf * 16;
  const long long brow0 = (long long)(n0 + srow) * K + shalf * 16;

  for (int k0 = 0; k0 < K; k0 += 32) {
    GLD_LDS16(Sb + arow0 + k0, &As[wave * 1024]);
    GLD_LDS16(Sb + brow0 + k0, &Bs[wave * 1024]);
    __syncthreads();
    long af[4], bfr[4];
#pragma unroll
    for (int i = 0; i < 4; ++i)
      af[i] = *(const long*)(&As[(wm + i * 16 + l16) * 32 + quad * 8]);
#pragma unroll
    for (int j = 0; j < 4; ++j)
      bfr[j] = *(const long*)(&Bs[(wn + j * 16 + l16) * 32 + quad * 8]);
#pragma unroll
    for (int i = 0; i < 4; ++i)
#pragma unroll
      for (int j = 0; j < 4; ++j)
        acc[i][j] = __builtin_amdgcn_mfma_f32_16x16x32_fp8_fp8(af[i], bfr[j], acc[i][j], 0, 0, 0);
    __syncthreads();
  }

#pragma unroll
  for (int i = 0; i < 4; ++i) {
#pragma unroll
    for (int j = 0; j < 4; ++j) {
      uint8_t bv[4];
#pragma unroll
      for (int r = 0; r < 4; ++r) {
        int row = m0 + wm + i * 16 + quad * 4 + r;
        int col = n0 + wn + j * 16 + l16;
        uint8_t h = f2fp8(acc[i][j][r]);
        bv[r] = h;
        Gb[(long long)row * T + col] = h;
      }
      if (ti != tj) {
        int mrow = n0 + wn + j * 16 + l16;
        int mcol = m0 + wm + i * 16 + quad * 4;
        uchar4 pk = {bv[0], bv[1], bv[2], bv[3]};
        *(uchar4*)(&Gb[(long long)mrow * T + mcol]) = pk;
      }
    }
  }
}

// ------------------- fp8 succ GEMM: succ = relu(G@STs^T - S*wd) ------------
// A = G (fp8, lda=2048), B = STs (fp8, ldb=2048); C in/out aliases S (bf16).
__global__ __launch_bounds__(256) void succ_fp8_k(
    const uint8_t* __restrict__ G, const uint8_t* __restrict__ STs,
    uint16_t* __restrict__ C, const float* __restrict__ wd,
    long long sG, long long sB, long long sC) {
  __shared__ __align__(16) uint8_t As[128 * 32];
  __shared__ __align__(16) uint8_t Bs[128 * 32];
  const int b = blockIdx.z;
  const uint8_t* Ab = G + (long long)b * sG;
  const uint8_t* Bb = STs + (long long)b * sB;
  uint16_t* Cb = C + (long long)b * sC;
  const float* wdb = wd + (long long)b * 2048;
  const int tid = threadIdx.x;
  const int lane = tid & 63;
  const int wave = tid >> 6;
  const int m0 = blockIdx.x * 128;
  const int n0 = blockIdx.y * 128;
  const int wm = (wave & 1) * 64;
  const int wn = (wave >> 1) * 64;
  const int quad = lane >> 4;
  const int l16 = lane & 15;
  const int K = 2048, N = 2048;

  f32x4 acc[4][4];
#pragma unroll
  for (int i = 0; i < 4; ++i)
#pragma unroll
    for (int j = 0; j < 4; ++j) acc[i][j] = (f32x4){0.f, 0.f, 0.f, 0.f};

  const int srow = wave * 32 + (lane >> 1);
  const int shalf = lane & 1;
  const long long arow0 = (long long)(m0 + srow) * K + shalf * 16;
  const long long brow0 = (long long)(n0 + srow) * K + shalf * 16;

  for (int k0 = 0; k0 < K; k0 += 32) {
    GLD_LDS16(Ab + arow0 + k0, &As[wave * 1024]);
    GLD_LDS16(Bb + brow0 + k0, &Bs[wave * 1024]);
    __syncthreads();
    long af[4], bfr[4];
#pragma unroll
    for (int i = 0; i < 4; ++i)
      af[i] = *(const long*)(&As[(wm + i * 16 + l16) * 32 + quad * 8]);
#pragma unroll
    for (int j = 0; j < 4; ++j)
      bfr[j] = *(const long*)(&Bs[(wn + j * 16 + l16) * 32 + quad * 8]);
#pragma unroll
    for (int i = 0; i < 4; ++i)
#pragma unroll
      for (int j = 0; j < 4; ++j)
        acc[i][j] = __builtin_amdgcn_mfma_f32_16x16x32_fp8_fp8(af[i], bfr[j], acc[i][j], 0, 0, 0);
    __syncthreads();
  }

#pragma unroll
  for (int i = 0; i < 4; ++i) {
#pragma unroll
    for (int j = 0; j < 4; ++j) {
#pragma unroll
      for (int r = 0; r < 4; ++r) {
        int row = m0 + wm + i * 16 + quad * 4 + r;
        int col = n0 + wn + j * 16 + l16;
        long long o = (long long)row * N + col;
        float sv = bf2f(Cb[o]);
        float v = acc[i][j][r] - sv * wdb[col];
        Cb[o] = f2bf(v > 0.f ? v : 0.f);
      }
    }
  }
}

// ------- transpose+shift+wdiag: S (TxN bf16) -> STs (NxT fp8), wd ----------
// STs[n][t] = S[t+1][n] (zero at t=T-1); wd[n] += sum_t S[t][n]*S[t+1][n]
__global__ __launch_bounds__(256) void transpose_shift_wd_k(
    const uint16_t* __restrict__ S, uint8_t* __restrict__ STs,
    float* __restrict__ wd, int T, int N) {
  __shared__ uint16_t tile[65][72];
  __shared__ float wdl[64];
  int t0 = blockIdx.x * 64, n0 = blockIdx.y * 64, b = blockIdx.z;
  const uint16_t* Sb = S + (long long)b * T * N;
  for (int s = threadIdx.x; s < 65 * 8; s += 256) {
    int t = s >> 3, n8 = s & 7;
    u16x8 v = (u16x8){0, 0, 0, 0, 0, 0, 0, 0};
    if (t0 + t < T) v = *(const u16x8*)(Sb + (long long)(t0 + t) * N + n0 + n8 * 8);
    *(u16x8*)(&tile[t][n8 * 8]) = v;
  }
  if (threadIdx.x < 64) wdl[threadIdx.x] = 0.f;
  __syncthreads();
  uint8_t* STsb = STs + (long long)b * N * T;
  for (int s = threadIdx.x; s < 64 * 8; s += 256) {
    int n = s >> 3, t8 = s & 7;
    u8x8 c;
    float part = 0.f;
#pragma unroll
    for (int j = 0; j < 8; ++j) {
      float a = bf2f(tile[t8 * 8 + j][n]);
      float nb = bf2f(tile[t8 * 8 + j + 1][n]);
      c[j] = f2fp8(nb);
      part = fmaf(a, nb, part);
    }
    *(u8x8*)(STsb + (long long)(n0 + n) * T + t0 + t8 * 8) = c;
    atomicAdd(&wdl[n], part);
  }
  __syncthreads();
  if (threadIdx.x < 64)
    atomicAdd(&wd[(long long)b * N + n0 + threadIdx.x], wdl[threadIdx.x]);
}

// ---------------- topk1: exact top-64 + L2 norm, dual output ---------------
__global__ __launch_bounds__(256) void topk1_k(
    const uint16_t* __restrict__ H, uint16_t* __restrict__ Sbf,
    uint8_t* __restrict__ Sf8) {
  const long long row = blockIdx.x;
  const uint16_t* h = H + row * 2048;
  const int tid = threadIdx.x;
  u16x8 v = *(const u16x8*)(h + tid * 8);

  __shared__ int hist[256];
  __shared__ int scan[256];
  __shared__ int sel_bin, sel_need;
  __shared__ int cgt_sh;
  __shared__ float ss_sh;

  hist[tid] = 0;
  if (tid == 0) { cgt_sh = 0; ss_sh = 0.f; }
  __syncthreads();
#pragma unroll
  for (int i = 0; i < 8; ++i) atomicAdd(&hist[v[i] >> 8], 1);
  __syncthreads();
  scan[tid] = hist[tid];
  __syncthreads();
  for (int o = 1; o < 256; o <<= 1) {
    int x = scan[tid] + ((tid + o < 256) ? scan[tid + o] : 0);
    __syncthreads();
    scan[tid] = x;
    __syncthreads();
  }
  if (scan[tid] >= 64 && (tid == 255 || scan[tid + 1] < 64)) {
    sel_bin = tid;
    sel_need = 64 - ((tid == 255) ? 0 : scan[tid + 1]);
  }
  __syncthreads();
  const int b1 = sel_bin;
  const int need1 = sel_need;
  __syncthreads();

  hist[tid] = 0;
  __syncthreads();
#pragma unroll
  for (int i = 0; i < 8; ++i)
    if ((int)(v[i] >> 8) == b1) atomicAdd(&hist[v[i] & 255], 1);
  __syncthreads();
  scan[tid] = hist[tid];
  __syncthreads();
  for (int o = 1; o < 256; o <<= 1) {
    int x = scan[tid] + ((tid + o < 256) ? scan[tid + o] : 0);
    __syncthreads();
    scan[tid] = x;
    __syncthreads();
  }
  if (scan[tid] >= need1 && (tid == 255 || scan[tid + 1] < need1)) sel_bin = tid;
  __syncthreads();
  const unsigned thresh = ((unsigned)b1 << 8) | (unsigned)sel_bin;
  const float thf = bf2f(thresh);

  int cgt = 0, ctie = 0;
  float ssq = 0.f;
#pragma unroll
  for (int i = 0; i < 8; ++i) {
    unsigned u = v[i];
    if (u > thresh) { cgt++; float f = bf2f(u); ssq += f * f; }
    else if (u == thresh) ctie++;
  }
  atomicAdd(&cgt_sh, cgt);
  atomicAdd(&ss_sh, ssq);
  __syncthreads();
  scan[tid] = ctie;
  __syncthreads();
  for (int o = 1; o < 256; o <<= 1) {
    int x = scan[tid] + ((tid >= o) ? scan[tid - o] : 0);
    __syncthreads();
    scan[tid] = x;
    __syncthreads();
  }
  const int tie_base = scan[tid] - ctie;
  const int r = 64 - cgt_sh;
  const float sumsq = ss_sh + (float)r * thf * thf;
  const float inv = 1.f / fmaxf(sqrtf(sumsq), 1e-10f);

  u16x8 o16;
  u8x8 o8;
  int tseen = 0;
#pragma unroll
  for (int i = 0; i < 8; ++i) {
    unsigned u = v[i];
    bool sel = (u > thresh);
    if (u == thresh) { sel = (tie_base + tseen) < r; tseen++; }
    float nv = sel ? bf2f(u) * inv : 0.f;
    o16[i] = sel ? (unsigned short)f2bf(nv) : (unsigned short)0;
    o8[i] = sel ? f2fp8(nv) : (uint8_t)0;
  }
  *(u16x8*)(Sbf + row * 2048 + tid * 8) = o16;
  *(u8x8*)(Sf8 + row * 2048 + tid * 8) = o8;
}

// ------------- topk2 + final: selection -> gather upT -> out ---------------
__global__ __launch_bounds__(256) void topk2_final_k(
    const uint16_t* __restrict__ H, const float* __restrict__ x,
    const float* __restrict__ g, const uint16_t* __restrict__ upTb,
    float* __restrict__ out) {
  const long long row = blockIdx.x;
  const uint16_t* h = H + row * 2048;
  const int tid = threadIdx.x;
  u16x8 v = *(const u16x8*)(h + tid * 8);

  __shared__ int hist[256];
  __shared__ int scan[256];
  __shared__ int sel_bin, sel_need;
  __shared__ int cgt_sh;
  __shared__ float ss_sh;
  __shared__ int app_sh;
  __shared__ int sidx[64];
  __shared__ float sval[64];

  hist[tid] = 0;
  if (tid == 0) { cgt_sh = 0; ss_sh = 0.f; app_sh = 0; }
  __syncthreads();
#pragma unroll
  for (int i = 0; i < 8; ++i) atomicAdd(&hist[v[i] >> 8], 1);
  __syncthreads();
  scan[tid] = hist[tid];
  __syncthreads();
  for (int o = 1; o < 256; o <<= 1) {
    int x2 = scan[tid] + ((tid + o < 256) ? scan[tid + o] : 0);
    __syncthreads();
    scan[tid] = x2;
    __syncthreads();
  }
  if (scan[tid] >= 64 && (tid == 255 || scan[tid + 1] < 64)) {
    sel_bin = tid;
    sel_need = 64 - ((tid == 255) ? 0 : scan[tid + 1]);
  }
  __syncthreads();
  const int b1 = sel_bin;
  const int need1 = sel_need;
  __syncthreads();

  hist[tid] = 0;
  __syncthreads();
#pragma unroll
  for (int i = 0; i < 8; ++i)
    if ((int)(v[i] >> 8) == b1) atomicAdd(&hist[v[i] & 255], 1);
  __syncthreads();
  scan[tid] = hist[tid];
  __syncthreads();
  for (int o = 1; o < 256; o <<= 1) {
    int x2 = scan[tid] + ((tid + o < 256) ? scan[tid + o] : 0);
    __syncthreads();
    scan[tid] = x2;
    __syncthreads();
  }
  if (scan[tid] >= need1 && (tid == 255 || scan[tid + 1] < need1)) sel_bin = tid;
  __syncthreads();
  const unsigned thresh = ((unsigned)b1 << 8) | (unsigned)sel_bin;
  const float thf = bf2f(thresh);

  int cgt = 0, ctie = 0;
  float ssq = 0.f;
#pragma unroll
  for (int i = 0; i < 8; ++i) {
    unsigned u = v[i];
    if (u > thresh) { cgt++; float f = bf2f(u); ssq += f * f; }
    else if (u == thresh) ctie++;
  }
  atomicAdd(&cgt_sh, cgt);
  atomicAdd(&ss_sh, ssq);
  __syncthreads();
  scan[tid] = ctie;
  __syncthreads();
  for (int o = 1; o < 256; o <<= 1) {
    int x2 = scan[tid] + ((tid >= o) ? scan[tid - o] : 0);
    __syncthreads();
    scan[tid] = x2;
    __syncthreads();
  }
  const int tie_base = scan[tid] - ctie;
  const int r = 64 - cgt_sh;
  const float sumsq = ss_sh + (float)r * thf * thf;
  const float inv = 1.f / fmaxf(sqrtf(sumsq), 1e-10f);

  int tseen = 0;
#pragma unroll
  for (int i = 0; i < 8; ++i) {
    unsigned u = v[i];
    bool sel = (u > thresh);
    if (u == thresh) { sel = (tie_base + tseen) < r; tseen++; }
    if (sel) {
      int p = atomicAdd(&app_sh, 1);  // exactly 64 claims
      sidx[p] = tid * 8 + i;
      sval[p] = bf2f(u) * inv;
    }
  }
  __syncthreads();

  // gather: out[row][col] = x + g * sum_j sval[j]*upTb[sidx[j]][col]
  const int col = tid * 2;
  float a0 = 0.f, a1 = 0.f;
#pragma unroll 8
  for (int j = 0; j < 64; ++j) {
    float w = sval[j];
    uint32_t pk = *(const uint32_t*)(upTb + (long long)sidx[j] * 512 + col);
    a0 = fmaf(w, bf2f(pk & 0xFFFFu), a0);
    a1 = fmaf(w, bf2f(pk >> 16), a1);
  }
  long long o = row * 512 + col;
  float2 xv = *(const float2*)(x + o);
  float2 gv = *(const float2*)(g + o);
  float2 rr;
  rr.x = xv.x + gv.x * a0;
  rr.y = xv.y + gv.y * a1;
  *(float2*)(out + o) = rr;
}

// ---------------------------------------------------------------------------
extern "C" void kernel_launch(void* const* d_in, const int* in_sizes, int n_in,
                              void* d_out, int out_size, void* d_ws, size_t ws_size,
                              hipStream_t stream) {
  const float* x = (const float*)d_in[0];
  const float* downW = (const float*)d_in[1];
  const float* upW = (const float*)d_in[2];
  const float* gateW = (const float*)d_in[3];
  const float* gateB = (const float*)d_in[4];
  float* out = (float*)d_out;

  const int B = 8, T = 2048, D = 512, N = 2048;
  const long long BT = (long long)B * T;
  const long long TN = (long long)T * N;  // 4,194,304
  const long long TD = (long long)T * D;

  char* base = (char*)d_ws;
  size_t off = 0;
  auto take = [&](size_t bytes) {
    size_t o = off;
    off += (bytes + 255) & ~(size_t)255;
    return o;
  };
  size_t o_xb = take((size_t)BT * D * 2);   // 16 MiB
  size_t o_dwb = take((size_t)N * D * 2);   // 2 MiB
  size_t o_gwb = take((size_t)D * D * 2);   // 0.5 MiB
  size_t o_upT = take((size_t)N * D * 2);   // 2 MiB (bf16)
  const size_t fixed = off;
  // per batch: R1 (8 MiB), R2 (8 MiB), R3 (4 MiB), R4 (4 MiB), wd (8 KiB)
  const size_t perb = (size_t)TN * 2 + (size_t)TN * 2 + (size_t)TN +
                      (size_t)TN + (size_t)N * 4;
  int Bc = 1;
  if (ws_size >= fixed + 8 * perb) Bc = 8;
  else if (ws_size >= fixed + 4 * perb) Bc = 4;
  else if (ws_size >= fixed + 2 * perb) Bc = 2;

  uint16_t* xb = (uint16_t*)(base + o_xb);
  uint16_t* dwb = (uint16_t*)(base + o_dwb);
  uint16_t* gwb = (uint16_t*)(base + o_gwb);
  uint16_t* upTb = (uint16_t*)(base + o_upT);
  char* p = base + fixed;
  uint16_t* R1 = (uint16_t*)p; p += (size_t)TN * 2 * Bc;  // h (bf16) -> G (fp8)
  uint16_t* R2 = (uint16_t*)p; p += (size_t)TN * 2 * Bc;  // S (bf16) -> succ
  uint8_t* R3 = (uint8_t*)p;  p += (size_t)TN * Bc;       // STs fp8 -> g fp32
  uint8_t* R4 = (uint8_t*)p;  p += (size_t)TN * Bc;       // S fp8
  float* wd = (float*)p;

  // prep (once)
  cast_f32_bf16_k<<<2048, 256, 0, stream>>>(x, xb, BT * D);
  cast_f32_bf16_k<<<512, 256, 0, stream>>>(downW, dwb, (long long)N * D);
  cast_f32_bf16_k<<<128, 256, 0, stream>>>(gateW, gwb, (long long)D * D);
  transpose_upw_k<<<dim3(N / 32, D / 32), 256, 0, stream>>>(upW, upTb, D, N);

  const int ltri = 16 * 17 / 2;  // 136 lower-triangle 128x128 tiles

  for (int b0 = 0; b0 < B; b0 += Bc) {
    const uint16_t* xc = xb + (long long)b0 * TD;
    // h = relu(x @ down_W^T) -> R1 (bf16)
    gemm_bt_k<EPI_RELU_BF16><<<dim3(Bc * 16, 16, 1), 256, 0, stream>>>(
        xc, dwb, R1, nullptr, Bc * T, N, D);
    // S = l2norm(kwta(h)) -> R2 bf16 + R4 fp8
    topk1_k<<<Bc * T, 256, 0, stream>>>(R1, R2, R4);
    // STs (fp8) + wd
    zero_f32_k<<<(Bc * N + 255) / 256, 256, 0, stream>>>(wd, (long long)Bc * N);
    transpose_shift_wd_k<<<dim3(T / 64, N / 64, Bc), 256, 0, stream>>>(
        R2, R3, wd, T, N);
    // G = S·S^T (fp8, symmetric) -> R1 (h dead)
    gram_fp8_k<<<dim3(ltri, 1, Bc), 256, 0, stream>>>(
        R4, (uint8_t*)R1, TN, (long long)T * T);
    // succ = relu(G @ STs^T - S*wd) -> R2 in place
    succ_fp8_k<<<dim3(16, 16, Bc), 256, 0, stream>>>(
        (const uint8_t*)R1, R3, R2, wd, (long long)T * T, TN, TN);
    // g = sigmoid(x @ gate_W^T + b) -> R3 fp32 (STs dead)
    gemm_bt_k<EPI_SIG><<<dim3(Bc * 16, D / 128, 1), 256, 0, stream>>>(
        xc, gwb, (float*)R3, gateB, Bc * T, D, D);
    // topk2 + final fused
    topk2_final_k<<<Bc * T, 256, 0, stream>>>(
        R2, x + (long long)b0 * TD, (const float*)R3, upTb,
        out + (long long)b0 * TD);
  }
}